// Round 4
// baseline (12544.867 us; speedup 1.0000x reference)
//
#include <hip/hip_runtime.h>

typedef short bf16x8 __attribute__((ext_vector_type(8)));
typedef float f32x4 __attribute__((ext_vector_type(4)));
typedef unsigned short u16;
typedef unsigned int u32;

static constexpr int B = 2048, S = 128, D = 128, H = 256;
static constexpr size_t PH = (size_t)B * H;

// LDS layout (u16 units): W-resident 16x2048 | Ahi 2x8192 | Alo 2x8192 | projW 8x512
#define LDS_AHI  32768
#define LDS_ALO  49152
#define LDS_PW   65536
#define LDS_TOT  69632

__device__ __forceinline__ u16 f2bf(float x){ u32 u=__float_as_uint(x); return (u16)((u + 0x7fffu + ((u>>16)&1u))>>16); }
__device__ __forceinline__ float bf2f(u16 h){ return __uint_as_float(((u32)h)<<16); }
__device__ __forceinline__ float fsig(float x){ return 1.0f/(1.0f+__expf(-x)); }
__device__ __forceinline__ float ftanh(float x){ return 1.0f - 2.0f/(__expf(2.0f*x)+1.0f); }
__device__ __forceinline__ int swz(int row){ return (row ^ (row>>2)) & 3; }

__device__ __forceinline__ void gl_lds16(const void* gp, const u16* lp){
  __builtin_amdgcn_global_load_lds((const __attribute__((address_space(1))) void*)gp,
      (__attribute__((address_space(3))) void*)lp, 16, 0, 0);
}

__global__ __launch_bounds__(256) void cvtk(const float* __restrict__ s, u16* __restrict__ d, int n){
  int i = (blockIdx.x*256 + threadIdx.x)*4;
  if (i+3 < n){
    float4 v = *(const float4*)(s+i);
    d[i]=f2bf(v.x); d[i+1]=f2bf(v.y); d[i+2]=f2bf(v.z); d[i+3]=f2bf(v.w);
  }
}
__global__ __launch_bounds__(256) void addk(const float* __restrict__ a, const float* __restrict__ b,
                                            float* __restrict__ o, int n){
  int i = blockIdx.x*256 + threadIdx.x; if (i<n) o[i]=a[i]+b[i];
}

struct G {
  const float* x;
  const u16 *W0,*W1,*W2,*W3,*W4,*W5,*W6,*W7,*W8;
  const float* bs; const float* bout;
  u16* pl; float* out; u32* cnt;
};

struct LA {
  const float* xf; int t;              // if xf: A1 = fp32 x[:,t,:]
  const u16 *a1h,*a1l; int K1;
  const u16 *a2h,*a2l; int K2;
  size_t gb;                           // global batch-row base
  const float* bs;                     // bias sums (4H)
  u16 *hh,*hl;                         // h output planes
  int doprj; const float* bout; float* out; int tau;
};

// W-slice -> LDS, layout [tile][64][32] with 4-slot swizzle (linear dest, swizzled source)
__device__ __forceinline__ void stage_w(u16* lds, const u16* W1, int K1, const u16* W2, int K2,
                                        const int tid, const int n){
  const int n1 = K1>>5, nt = (K1+K2)>>5;
  for (int p=0; p<nt/2; ++p){
    const int id2 = p*512 + tid;
    const int tile = id2>>8, row = (id2>>2)&63, slot = id2&3, gq = slot ^ swz(row);
    const u16* Ws; int ldw, k0;
    if (tile < n1){ Ws=W1; ldw=K1; k0=tile*32; } else { Ws=W2; ldw=K2; k0=(tile-n1)*32; }
    const int grow = (row>>4)*H + n*16 + (row&15);
    gl_lds16(Ws + (size_t)grow*ldw + k0 + gq*8, &lds[p*4096 + (tid>>6)*512]);
  }
}
__device__ __forceinline__ void stage_pw(u16* lds, const u16* Wo, const int tid, const int n){
  const int row=(tid>>2)&15, tile=tid>>6, slot=tid&3, gq=slot^swz(row);
  gl_lds16(Wo + (size_t)(n*16+row)*H + tile*32 + gq*8, &lds[LDS_PW + (tid>>6)*512]);
  (void)tile; (void)slot;
}

// slice-local grid barrier (32 blocks), device-scope
__device__ __forceinline__ void sbar(u32* cnt, u32 target){
  __syncthreads();
  if (threadIdx.x == 0){
    __threadfence();
    __hip_atomic_fetch_add(cnt, 1u, __ATOMIC_RELEASE, __HIP_MEMORY_SCOPE_AGENT);
    while (__hip_atomic_load(cnt, __ATOMIC_ACQUIRE, __HIP_MEMORY_SCOPE_AGENT) < target)
      __builtin_amdgcn_s_sleep(2);
    __threadfence();
  }
  __syncthreads();
}

template<int MF>   // MF = BM/128 (1: dec half-batch, 2: enc full slice)
__device__ __forceinline__ void run_layer(u16* lds, const LA& A, const int tid,
    const int w, const int lr, const int lc, const int n,
    float (&c0)[4], float (&c1)[4])
{
  const int n1 = A.K1>>5, nt = (A.K1+A.K2)>>5;
  f32x4 acc[MF][4];
  #pragma unroll
  for (int mf=0; mf<MF; ++mf)
    #pragma unroll
    for (int q=0; q<4; ++q) acc[mf][q] = (f32x4){0.f,0.f,0.f,0.f};
  f32x4 accp = {0.f,0.f,0.f,0.f};

  auto stage = [&](int tile, int buf){
    const int abase = LDS_AHI + buf*8192, lbase = LDS_ALO + buf*8192;
    if (A.xf && tile < n1){
      const int k0 = tile*32;
      #pragma unroll
      for (int p=0; p<MF; ++p){
        const int id2 = p*512 + tid;
        const int row = id2>>2, slot = id2&3, gq = slot ^ swz(row);
        const float* src = A.xf + ((A.gb + row)*S + A.t)*D + k0 + gq*8;
        f32x4 v0 = *(const f32x4*)src;
        f32x4 v1 = *(const f32x4*)(src+4);
        float vv[8]; *(f32x4*)vv = v0; *(f32x4*)(vv+4) = v1;
        u16 h8[8], l8[8];
        #pragma unroll
        for (int i=0;i<8;i++){ u16 hb=f2bf(vv[i]); h8[i]=hb; l8[i]=f2bf(vv[i]-bf2f(hb)); }
        *(bf16x8*)&lds[abase + id2*8] = *(bf16x8*)h8;
        *(bf16x8*)&lds[lbase + id2*8] = *(bf16x8*)l8;
      }
    } else {
      const u16 *sh, *sl; int k0;
      if (tile < n1){ sh=A.a1h; sl=A.a1l; k0=tile*32; }
      else          { sh=A.a2h; sl=A.a2l; k0=(tile-n1)*32; }
      #pragma unroll
      for (int p=0; p<MF; ++p){
        const int id2 = p*512 + tid;
        const int row = id2>>2, slot = id2&3, gq = slot ^ swz(row);
        const size_t off = (A.gb + row)*H + k0 + gq*8;
        gl_lds16(sh + off, &lds[abase + p*4096 + (tid>>6)*512]);
        gl_lds16(sl + off, &lds[lbase + p*4096 + (tid>>6)*512]);
      }
    }
  };

  stage(0, 0);
  asm volatile("s_waitcnt vmcnt(0) lgkmcnt(0)" ::: "memory");
  __builtin_amdgcn_s_barrier();

  for (int tile=0; tile<nt; ++tile){
    const int buf = tile & 1;
    if (tile+1 < nt) stage(tile+1, buf^1);
    {
      const int as2 = LDS_AHI + buf*8192, ls2 = LDS_ALO + buf*8192;
      bf16x8 ah[MF], al[MF];
      #pragma unroll
      for (int mf=0; mf<MF; ++mf){
        const int row = w*(16*MF) + mf*16 + lr;
        const int off = row*32 + (lc ^ swz(row))*8;
        ah[mf] = *(const bf16x8*)&lds[as2 + off];
        al[mf] = *(const bf16x8*)&lds[ls2 + off];
      }
      #pragma unroll
      for (int q=0; q<4; ++q){
        const int nr = q*16 + lr;
        bf16x8 bg = *(const bf16x8*)&lds[tile*2048 + nr*32 + (lc ^ swz(nr))*8];
        #pragma unroll
        for (int mf=0; mf<MF; ++mf){
          acc[mf][q] = __builtin_amdgcn_mfma_f32_16x16x32_bf16(ah[mf], bg, acc[mf][q], 0,0,0);
          acc[mf][q] = __builtin_amdgcn_mfma_f32_16x16x32_bf16(al[mf], bg, acc[mf][q], 0,0,0);
        }
      }
      if (A.doprj && tile < 8){
        bf16x8 bp = *(const bf16x8*)&lds[LDS_PW + tile*512 + lr*32 + (lc ^ swz(lr))*8];
        accp = __builtin_amdgcn_mfma_f32_16x16x32_bf16(ah[0], bp, accp, 0,0,0);
        accp = __builtin_amdgcn_mfma_f32_16x16x32_bf16(al[0], bp, accp, 0,0,0);
      }
    }
    asm volatile("s_waitcnt vmcnt(0) lgkmcnt(0)" ::: "memory");
    __builtin_amdgcn_s_barrier();
  }

  {
    const int j = n*16 + lr;
    const float bi_=A.bs[j], bf_=A.bs[H+j], bg_=A.bs[2*H+j], bo_=A.bs[3*H+j];
    #pragma unroll
    for (int mf=0; mf<MF; ++mf){
      #pragma unroll
      for (int r=0; r<4; ++r){
        const size_t m = A.gb + w*(16*MF) + mf*16 + lc*4 + r;
        const size_t idx = m*H + j;
        const float ig = fsig (acc[mf][0][r] + bi_);
        const float fg = fsig (acc[mf][1][r] + bf_);
        const float g_ = ftanh(acc[mf][2][r] + bg_);
        const float og = fsig (acc[mf][3][r] + bo_);
        const float cp = (MF==2 && mf==1) ? c1[r] : c0[r];
        const float c  = fg*cp + ig*g_;
        if (MF==2 && mf==1) c1[r] = c; else c0[r] = c;
        const float h  = og * ftanh(c);
        const u16 hb = f2bf(h);
        A.hh[idx] = hb;
        A.hl[idx] = f2bf(h - bf2f(hb));
      }
    }
    if (A.doprj){
      const int col = n*16 + lr;
      const float bo = A.bout[col];
      #pragma unroll
      for (int r=0; r<4; ++r){
        const size_t m = A.gb + w*16 + lc*4 + r;
        A.out[(m*S + A.tau)*D + col] = accp[r] + bo;
      }
    }
  }
}

__device__ __forceinline__ void run_proj(u16* lds, const u16* ah0, const u16* al0,
    size_t gb, int tau, const float* bout, float* out,
    const int tid, const int w, const int lr, const int lc, const int n)
{
  f32x4 accp = {0.f,0.f,0.f,0.f};
  auto stg = [&](int tile, int buf){
    const int row = tid>>2, slot = tid&3, gq = slot ^ swz(row);
    const size_t off = (gb + row)*H + tile*32 + gq*8;
    gl_lds16(ah0 + off, &lds[LDS_AHI + buf*8192 + (tid>>6)*512]);
    gl_lds16(al0 + off, &lds[LDS_ALO + buf*8192 + (tid>>6)*512]);
  };
  stg(0, 0);
  asm volatile("s_waitcnt vmcnt(0)" ::: "memory");
  __builtin_amdgcn_s_barrier();
  for (int tile=0; tile<8; ++tile){
    const int buf = tile&1;
    if (tile+1 < 8) stg(tile+1, buf^1);
    const int row = w*16 + lr;
    const int off = row*32 + (lc ^ swz(row))*8;
    bf16x8 a1 = *(const bf16x8*)&lds[LDS_AHI + buf*8192 + off];
    bf16x8 a2 = *(const bf16x8*)&lds[LDS_ALO + buf*8192 + off];
    bf16x8 bp = *(const bf16x8*)&lds[LDS_PW + tile*512 + lr*32 + (lc ^ swz(lr))*8];
    accp = __builtin_amdgcn_mfma_f32_16x16x32_bf16(a1, bp, accp, 0,0,0);
    accp = __builtin_amdgcn_mfma_f32_16x16x32_bf16(a2, bp, accp, 0,0,0);
    asm volatile("s_waitcnt vmcnt(0)" ::: "memory");
    __builtin_amdgcn_s_barrier();
  }
  const int col = n*16 + lr;
  const float bo = bout[col];
  #pragma unroll
  for (int r=0; r<4; ++r){
    const size_t m = gb + w*16 + lc*4 + r;
    out[(m*S + tau)*D + col] = accp[r] + bo;
  }
}

__global__ __launch_bounds__(512, 1) void persist(G g)
{
  __shared__ u16 lds[LDS_TOT];
  const int tid = threadIdx.x, w = tid>>6, l = tid&63, lr = l&15, lc = l>>4;
  const int bid = blockIdx.x, slice = bid&7, bi2 = bid>>3, role = bi2>>4, n = bi2&15;
  u32* cnt = g.cnt + slice*16;
  float cA[4] = {0,0,0,0}, cB[4] = {0,0,0,0};
  auto pln = [&](int i){ return g.pl + (size_t)i*PH; };
  const size_t sb = (size_t)slice*256;

  if (role==0) stage_w(lds, g.W0, D, g.W1, H, tid, n);
  else         stage_w(lds, g.W2, H, g.W3, H, tid, n);
  asm volatile("s_waitcnt vmcnt(0)" ::: "memory");
  __syncthreads();

  for (int p=0; p<387; ++p){
    if (role==0){
      if (p<=127){
        const int t=p, pr=t&1, pw_=(t+1)&1;
        LA A; A.xf=g.x; A.t=t; A.a1h=nullptr; A.a1l=nullptr; A.K1=D;
        A.a2h=pln(0+2*pr); A.a2l=pln(1+2*pr); A.K2=H;
        A.gb=sb; A.bs=g.bs; A.hh=pln(0+2*pw_); A.hl=pln(1+2*pw_);
        A.doprj=0; A.bout=nullptr; A.out=nullptr; A.tau=0;
        run_layer<2>(lds, A, tid, w, lr, lc, n, cA, cB);
      } else if (p==128){
        stage_w(lds, g.W4, H, g.W5, H, tid, n);
        if (n<8) stage_pw(lds, g.W8, tid, n);
        asm volatile("s_waitcnt vmcnt(0)" ::: "memory");
        __syncthreads();
        #pragma unroll
        for (int r=0;r<4;++r){ cA[r]=0.f; cB[r]=0.f; }
      } else {
        const int q = p-129;
        if (q<=255){
          const int t=q>>1, h=q&1, pr=t&1, pw_=(t+1)&1;
          LA A; A.xf=nullptr; A.t=0;
          if (t==0){ A.a1h=pln(4); A.a1l=pln(5); }          // encoded = eh2 par0
          else     { A.a1h=pln(12+2*pr); A.a1l=pln(13+2*pr); }
          A.K1=H;
          A.a2h=pln(8+2*pr); A.a2l=pln(9+2*pr); A.K2=H;
          A.gb=sb + (size_t)h*128;
          A.bs=g.bs + 2048;
          A.hh=pln(8+2*pw_); A.hl=pln(9+2*pw_);
          A.doprj=(n<8 && t>=1) ? 1:0; A.bout=g.bout; A.out=g.out; A.tau=t-1;
          if (h==0) run_layer<1>(lds, A, tid, w, lr, lc, n, cA, cA);
          else      run_layer<1>(lds, A, tid, w, lr, lc, n, cB, cB);
        } else {
          const int h = q-256;           // p=385,386 -> standalone proj(127,h)
          if (h<=1 && n<8)
            run_proj(lds, pln(12), pln(13), sb+(size_t)h*128, 127, g.bout, g.out, tid, w, lr, lc, n);
        }
      }
    } else {
      if (p>=1 && p<=128){
        const int t=p-1, pr=t&1, pw_=(t+1)&1;
        LA A; A.xf=nullptr; A.t=0;
        A.a1h=pln(0+2*pw_); A.a1l=pln(1+2*pw_); A.K1=H;     // eh1[(t+1)&1]
        A.a2h=pln(4+2*pr);  A.a2l=pln(5+2*pr);  A.K2=H;     // eh2[t&1]
        A.gb=sb; A.bs=g.bs+1024;
        A.hh=pln(4+2*pw_); A.hl=pln(5+2*pw_);
        A.doprj=0; A.bout=nullptr; A.out=nullptr; A.tau=0;
        run_layer<2>(lds, A, tid, w, lr, lc, n, cA, cB);
      } else if (p==129){
        stage_w(lds, g.W6, H, g.W7, H, tid, n);
        asm volatile("s_waitcnt vmcnt(0)" ::: "memory");
        __syncthreads();
        #pragma unroll
        for (int r=0;r<4;++r){ cA[r]=0.f; cB[r]=0.f; }
      } else if (p>=130){
        const int r2 = p-130;
        if (r2<=255){
          const int t=r2>>1, h=r2&1, pr=t&1, pw_=(t+1)&1;
          LA A; A.xf=nullptr; A.t=0;
          A.a1h=pln(8+2*pw_); A.a1l=pln(9+2*pw_); A.K1=H;   // dh1[(t+1)&1]
          A.a2h=pln(12+2*pr); A.a2l=pln(13+2*pr); A.K2=H;   // dh2[t&1]
          A.gb=sb + (size_t)h*128;
          A.bs=g.bs + 3072;
          A.hh=pln(12+2*pw_); A.hl=pln(13+2*pw_);
          A.doprj=0; A.bout=nullptr; A.out=nullptr; A.tau=0;
          if (h==0) run_layer<1>(lds, A, tid, w, lr, lc, n, cA, cA);
          else      run_layer<1>(lds, A, tid, w, lr, lc, n, cB, cB);
        }
      }
    }
    sbar(cnt, 32u*(u32)(p+1));
  }
}

extern "C" void kernel_launch(void* const* d_in, const int* in_sizes, int n_in,
                              void* d_out, int out_size, void* d_ws, size_t ws_size,
                              hipStream_t stream)
{
  const float* x     = (const float*)d_in[0];
  const float* eWih0 = (const float*)d_in[1];
  const float* eWhh0 = (const float*)d_in[2];
  const float* ebih0 = (const float*)d_in[3];
  const float* ebhh0 = (const float*)d_in[4];
  const float* eWih1 = (const float*)d_in[5];
  const float* eWhh1 = (const float*)d_in[6];
  const float* ebih1 = (const float*)d_in[7];
  const float* ebhh1 = (const float*)d_in[8];
  const float* dWih0 = (const float*)d_in[9];
  const float* dWhh0 = (const float*)d_in[10];
  const float* dbih0 = (const float*)d_in[11];
  const float* dbhh0 = (const float*)d_in[12];
  const float* dWih1 = (const float*)d_in[13];
  const float* dWhh1 = (const float*)d_in[14];
  const float* dbih1 = (const float*)d_in[15];
  const float* dbhh1 = (const float*)d_in[16];
  const float* Wout  = (const float*)d_in[17];
  const float* bout  = (const float*)d_in[18];
  float* out = (float*)d_out;

  u16* wc = (u16*)d_ws;
  const int szW[9] = {4*H*D, 4*H*H, 4*H*H, 4*H*H, 4*H*H, 4*H*H, 4*H*H, 4*H*H, D*H};
  const float* srcW[9] = {eWih0,eWhh0,eWih1,eWhh1,dWih0,dWhh0,dWih1,dWhh1,Wout};
  u16* dstW[9]; size_t woff = 0;
  for (int i=0;i<9;i++){ dstW[i] = wc + woff; woff += (size_t)szW[i]; }
  woff = (woff + 7) & ~(size_t)7;
  float* bs = (float*)(wc + woff);
  u16* pl  = (u16*)(bs + 4*1024);
  u32* cnt = (u32*)(pl + 16*PH);

  for (int i=0;i<9;i++)
    cvtk<<<dim3((szW[i]+1023)/1024), dim3(256), 0, stream>>>(srcW[i], dstW[i], szW[i]);
  addk<<<dim3(4), dim3(256), 0, stream>>>(ebih0, ebhh0, bs,        1024);
  addk<<<dim3(4), dim3(256), 0, stream>>>(ebih1, ebhh1, bs+1024,   1024);
  addk<<<dim3(4), dim3(256), 0, stream>>>(dbih0, dbhh0, bs+2048,   1024);
  addk<<<dim3(4), dim3(256), 0, stream>>>(dbih1, dbhh1, bs+3072,   1024);
  hipMemsetAsync(pl, 0, 16*PH*sizeof(u16) + 1024, stream);  // h planes + barrier counters

  G g;
  g.x = x;
  g.W0=dstW[0]; g.W1=dstW[1]; g.W2=dstW[2]; g.W3=dstW[3];
  g.W4=dstW[4]; g.W5=dstW[5]; g.W6=dstW[6]; g.W7=dstW[7]; g.W8=dstW[8];
  g.bs = bs; g.bout = bout; g.pl = pl; g.out = out; g.cnt = cnt;
  persist<<<dim3(256), dim3(512), 0, stream>>>(g);
}

// Round 6
// 6526.476 us; speedup vs baseline: 1.9222x; 1.9222x over previous
//
#include <hip/hip_runtime.h>

typedef short bf16x8 __attribute__((ext_vector_type(8)));
typedef float f32x4 __attribute__((ext_vector_type(4)));
typedef unsigned short u16;
typedef unsigned int u32;
typedef unsigned long long u64;

static constexpr int B = 2048, S = 128, D = 128, H = 256;
static constexpr size_t PH = (size_t)B * H;

// LDS layout (u16 units), 64 KiB total:
//   Wb: 3 ring buffers x 4096 (8KB)   [0, 12288)
//   Wp: proj weights 4096 (8KB)       [12288, 16384)
//   Ab: 2 bufs x (hi 4096 | lo 4096)  [16384, 32768)
#define L_WB   0
#define L_WP   12288
#define L_AHI  16384
#define L_ALO  20480
#define L_TOT  32768

__device__ __forceinline__ u16 f2bf(float x){ u32 u=__float_as_uint(x); return (u16)((u + 0x7fffu + ((u>>16)&1u))>>16); }
__device__ __forceinline__ float bf2f(u16 h){ return __uint_as_float(((u32)h)<<16); }
__device__ __forceinline__ float fsig(float x){ return 1.0f/(1.0f+__expf(-x)); }
__device__ __forceinline__ float ftanh(float x){ return 1.0f - 2.0f/(__expf(2.0f*x)+1.0f); }
__device__ __forceinline__ int swz(int r){ return (r ^ (r>>2)) & 3; }

__device__ __forceinline__ void gl_lds16(const void* g, const u16* l){
  __builtin_amdgcn_global_load_lds((const __attribute__((address_space(1))) void*)g,
      (__attribute__((address_space(3))) void*)l, 16, 0, 0);
}
// device-scope coherent data access, relaxed => no cache-maintenance instructions
__device__ __forceinline__ u64 ald64(const u32* p){
  return __hip_atomic_load((const u64*)p, __ATOMIC_RELAXED, __HIP_MEMORY_SCOPE_AGENT);
}
__device__ __forceinline__ void ast32(u32* p, u32 v){
  __hip_atomic_store(p, v, __ATOMIC_RELAXED, __HIP_MEMORY_SCOPE_AGENT);
}

__global__ __launch_bounds__(256) void cvtk(const float* __restrict__ s, u16* __restrict__ d, int n){
  int i = (blockIdx.x*256 + threadIdx.x)*4;
  if (i+3 < n){
    float4 v = *(const float4*)(s+i);
    d[i]=f2bf(v.x); d[i+1]=f2bf(v.y); d[i+2]=f2bf(v.z); d[i+3]=f2bf(v.w);
  }
}
__global__ __launch_bounds__(256) void addk(const float* __restrict__ a, const float* __restrict__ b,
                                            float* __restrict__ o, int n){
  int i = blockIdx.x*256 + threadIdx.x; if (i<n) o[i]=a[i]+b[i];
}

// One LSTM-layer (or proj-fused) phase job
struct Ph {
  const float* xf; int t;            // fp32 x source (enc L0 first tiles) or null
  const u32 *A1, *A2; int n1, n2;    // packed hi|lo u32 planes; tile counts
  const u16 *W1, *W2; int ldw1, ldw2;
  size_t gb;                         // batch-row base for this job (M = 64*MF rows)
  const float* bs;                   // fused bias (4H fp32)
  u32* outP;                         // h output plane (packed hi|lo)
  int doprj; const float* bout; float* out; int tau;
};

// 8 waves. MF=2: block tile 128 rows x 64 j-cols; MF=1: 64 rows x 64 j-cols.
// m-group = w>>1 (4 groups), n-half = w&1; frag q = gate q at j = n*32+(w&1)*16+lr.
template<int MF>
__device__ __forceinline__ void run_layer(u16* lds, const Ph& J,
    const int tid, const int w, const int lr, const int lc, const int n,
    float (&cst)[MF][4])
{
  const int nt = J.n1 + J.n2;
  const int M4 = MF * 256;                 // active A-staging threads

  // A staging: thread covers (srow, 8 k at koct); linear global read, swizzled LDS slot
  const int srow = tid >> 2, koct = tid & 3;
  const int adst = srow*32 + ((koct ^ swz(srow))*8);
  // W staging: gl_lds16 linear dest => swizzled global source octet
  const int wrow = tid >> 2, wslot = tid & 3, wgq = wslot ^ swz(wrow);
  const int f_ = wrow >> 4;                // frag 0..7
  const int zrow = (f_ & 3)*H + n*32 + ((f_ >> 2) << 4) + (wrow & 15);

  int aoff[MF];
  #pragma unroll
  for (int mf = 0; mf < MF; ++mf){
    const int r = (w>>1)*(16*MF) + mf*16 + lr;
    aoff[mf] = r*32 + ((lc ^ swz(r))*8);
  }
  int woff[4];
  #pragma unroll
  for (int q = 0; q < 4; ++q){
    const int nr = (w&1)*64 + q*16 + lr;
    woff[q] = nr*32 + ((lc ^ swz(nr))*8);
  }
  const int poff = lr*32 + ((lc ^ swz(lr))*8);

  f32x4 acc[MF][4];
  #pragma unroll
  for (int mf=0; mf<MF; ++mf)
    #pragma unroll
    for (int q=0; q<4; ++q) acc[mf][q] = (f32x4){0.f,0.f,0.f,0.f};
  f32x4 accp = {0.f,0.f,0.f,0.f};

  u64 rA0[4], rA1[4];

  auto issue = [&](int tile, u64 (&rA)[4], int wb){
    // W dma FIRST: a later vmcnt wait on this tile's A regs implies the dma retired
    const u16* Ws = (tile < J.n1) ? J.W1 : J.W2;
    const int  ldw = (tile < J.n1) ? J.ldw1 : J.ldw2;
    const int  k0 = ((tile < J.n1) ? tile : tile - J.n1) << 5;
    gl_lds16(Ws + (size_t)zrow*ldw + k0 + wgq*8, &lds[L_WB + wb*4096 + (tid>>6)*512]);
    if (tid < M4){
      if (J.xf && tile < J.n1){
        const float* src = J.xf + ((J.gb + srow)*S + J.t)*D + k0 + koct*8;
        #pragma unroll
        for (int i = 0; i < 4; ++i) rA[i] = *(const u64*)(src + 2*i);
      } else {
        const u32* pl = (tile < J.n1) ? J.A1 : J.A2;
        const u32* src = pl + (J.gb + srow)*H + k0 + koct*8;
        #pragma unroll
        for (int i = 0; i < 4; ++i) rA[i] = ald64(src + 2*i);
      }
    }
  };
  auto commit = [&](int tile, u64 (&rA)[4], int ab){
    if (tid < M4){
      u16 hi8[8], lo8[8];
      if (J.xf && tile < J.n1){
        #pragma unroll
        for (int i = 0; i < 4; ++i){
          float f0 = __uint_as_float((u32)rA[i]);
          float f1 = __uint_as_float((u32)(rA[i] >> 32));
          u16 h0 = f2bf(f0); hi8[2*i]   = h0; lo8[2*i]   = f2bf(f0 - bf2f(h0));
          u16 h1 = f2bf(f1); hi8[2*i+1] = h1; lo8[2*i+1] = f2bf(f1 - bf2f(h1));
        }
      } else {
        #pragma unroll
        for (int i = 0; i < 4; ++i){
          u32 e0 = (u32)rA[i], e1 = (u32)(rA[i] >> 32);
          hi8[2*i]   = (u16)(e0 >> 16); lo8[2*i]   = (u16)e0;
          hi8[2*i+1] = (u16)(e1 >> 16); lo8[2*i+1] = (u16)e1;
        }
      }
      *(bf16x8*)&lds[L_AHI + ab*8192 + adst] = *(bf16x8*)hi8;
      *(bf16x8*)&lds[L_ALO + ab*8192 + adst] = *(bf16x8*)lo8;
    }
  };

  // prologue: 2 tiles in flight
  issue(0, rA0, 0);
  issue(1, rA1, 1);
  commit(0, rA0, 0);   // A-waves: compiler vmcnt wait on rA0 => W(0) dma retired too
  if (M4 < 512 && tid >= M4)
    asm volatile("s_waitcnt vmcnt(1)" ::: "memory");   // non-A waves: retire W(0)
  asm volatile("s_waitcnt lgkmcnt(0)" ::: "memory");
  __builtin_amdgcn_s_barrier();

  for (int t = 0; t < nt; ++t){
    if (t + 2 < nt){
      if ((t & 1) == 0) issue(t+2, rA0, (t+2)%3);
      else              issue(t+2, rA1, (t+2)%3);
    }
    if (t + 1 < nt){
      if (((t+1) & 1) == 0) commit(t+1, rA0, 0);
      else                  commit(t+1, rA1, 1);
    }
    {
      const int ab = t & 1, wb = t % 3;
      bf16x8 ah[MF], al[MF];
      #pragma unroll
      for (int mf = 0; mf < MF; ++mf){
        ah[mf] = *(const bf16x8*)&lds[L_AHI + ab*8192 + aoff[mf]];
        al[mf] = *(const bf16x8*)&lds[L_ALO + ab*8192 + aoff[mf]];
      }
      #pragma unroll
      for (int q = 0; q < 4; ++q){
        bf16x8 bq = *(const bf16x8*)&lds[L_WB + wb*4096 + woff[q]];
        #pragma unroll
        for (int mf = 0; mf < MF; ++mf){
          acc[mf][q] = __builtin_amdgcn_mfma_f32_16x16x32_bf16(ah[mf], bq, acc[mf][q], 0,0,0);
          acc[mf][q] = __builtin_amdgcn_mfma_f32_16x16x32_bf16(al[mf], bq, acc[mf][q], 0,0,0);
        }
      }
      if (J.doprj && (w & 1) == 0 && t < 8){
        bf16x8 bp = *(const bf16x8*)&lds[L_WP + t*512 + poff];
        accp = __builtin_amdgcn_mfma_f32_16x16x32_bf16(ah[0], bp, accp, 0,0,0);
        accp = __builtin_amdgcn_mfma_f32_16x16x32_bf16(al[0], bp, accp, 0,0,0);
      }
    }
    // non-A waves must retire W(t+1) before the barrier that precedes its use.
    // (A-waves get this implicitly from commit(t+1)'s compiler vmcnt wait.)
    if (M4 < 512 && tid >= M4){
      if (t + 2 < nt) asm volatile("s_waitcnt vmcnt(1)" ::: "memory");
      else            asm volatile("s_waitcnt vmcnt(0)" ::: "memory");
    }
    asm volatile("s_waitcnt lgkmcnt(0)" ::: "memory");
    __builtin_amdgcn_s_barrier();
  }

  // epilogue: gates -> c,h ; packed coherent h store
  {
    const int j = n*32 + (w&1)*16 + lr;
    const float b0 = J.bs[j], b1 = J.bs[H+j], b2 = J.bs[2*H+j], b3 = J.bs[3*H+j];
    #pragma unroll
    for (int mf = 0; mf < MF; ++mf){
      #pragma unroll
      for (int r = 0; r < 4; ++r){
        const size_t m = J.gb + (size_t)(w>>1)*(16*MF) + mf*16 + lc*4 + r;
        const float ig = fsig (acc[mf][0][r] + b0);
        const float fg = fsig (acc[mf][1][r] + b1);
        const float gg = ftanh(acc[mf][2][r] + b2);
        const float og = fsig (acc[mf][3][r] + b3);
        const float c  = fg*cst[mf][r] + ig*gg;
        cst[mf][r] = c;
        const float h = og * ftanh(c);
        const u16 hb = f2bf(h);
        const u16 lb = f2bf(h - bf2f(hb));
        ast32(J.outP + m*H + j, ((u32)hb << 16) | lb);
      }
    }
    if (J.doprj && (w & 1) == 0){
      const int col = n*16 + lr;
      const float bo = J.bout[col];
      #pragma unroll
      for (int r = 0; r < 4; ++r){
        const size_t m = J.gb + (size_t)(w>>1)*(16*MF) + lc*4 + r;
        J.out[(m*S + J.tau)*D + col] = accp[r] + bo;
      }
    }
  }
}

struct GG {
  const float* x;
  const u16* W[9];
  const float* bs; const float* bout;
  u32* P;           // 9 packed planes of B*H u32 (8 live + 1 sink), then counters
  float* out; u32* cnt;
};

// planes: 0,1: eh1[2]  2,3: eh2[2]  4,5: dh1[2]  6,7: dh2[2]  8: sink
__global__ __launch_bounds__(512, 1) void persist(GG g)
{
  __shared__ u16 lds[L_TOT];
  const int tid = threadIdx.x, w = tid>>6, l = tid&63, lr = l&15, lc = l>>4;
  const int bid = blockIdx.x;
  const int slice = bid & 15, idx = bid >> 4, role = idx >> 3, n = idx & 7;
  const size_t gb0 = (size_t)slice * 128;
  u32* cnt = g.cnt + slice*64;
  auto P = [&](int i){ return g.P + (size_t)i * PH; };

  // proj weights resident (8KB, once)
  {
    const int prow = (tid>>2)&15, ps = tid&3, pg = ps ^ swz(prow);
    gl_lds16(g.W[8] + (size_t)(n*16 + prow)*H + (tid>>6)*32 + pg*8,
             &lds[L_WP + (tid>>6)*512]);
  }
  asm volatile("s_waitcnt vmcnt(0)" ::: "memory");
  __syncthreads();

  float cE[2][4] = {{0,0,0,0},{0,0,0,0}};
  float cD0[1][4] = {{0,0,0,0}};
  float cD1[1][4] = {{0,0,0,0}};

  for (int p = 0; p < 388; ++p){
    if (role == 0){
      if (p < 128){
        const int t = p, pr = t&1, pw = (t+1)&1;
        Ph J{g.x, t, nullptr, P(0+pr), 4, 8, g.W[0], g.W[1], D, H,
             gb0, g.bs, P(0+pw), 0, nullptr, nullptr, 0};
        run_layer<2>(lds, J, tid, w, lr, lc, n, cE);
      } else if (p >= 129 && p <= 384){
        const int q = p-129, t = q>>1, h = q&1, pr = t&1, pw = (t+1)&1;
        const u32* a1 = (t == 0) ? P(2) : P(6+pr);
        Ph J{nullptr, 0, a1, P(4+pr), 8, 8, g.W[4], g.W[5], H, H,
             gb0 + (size_t)h*64, g.bs + 2048, P(4+pw),
             (t >= 1) ? 1 : 0, g.bout, g.out, t-1};
        if (h == 0) run_layer<1>(lds, J, tid, w, lr, lc, n, cD0);
        else        run_layer<1>(lds, J, tid, w, lr, lc, n, cD1);
      } else if (p >= 386){
        // tail proj(tau=127) for half h = p-386: junk LSTM into sink plane
        const int h = p - 386;
        Ph J{nullptr, 0, P(6), P(4), 8, 8, g.W[4], g.W[5], H, H,
             gb0 + (size_t)h*64, g.bs + 2048, P(8), 1, g.bout, g.out, 127};
        float cj[1][4] = {{0,0,0,0}};
        run_layer<1>(lds, J, tid, w, lr, lc, n, cj);
      }
      // p==128, p==385 idle
    } else {
      if (p >= 1 && p <= 128){
        const int t = p-1, pr = t&1, pw = (t+1)&1;
        Ph J{nullptr, 0, P(0+pw), P(2+pr), 8, 8, g.W[2], g.W[3], H, H,
             gb0, g.bs + 1024, P(2+pw), 0, nullptr, nullptr, 0};
        run_layer<2>(lds, J, tid, w, lr, lc, n, cE);
      } else if (p >= 130 && p <= 385){
        const int r2 = p-130, t = r2>>1, h = r2&1, pr = t&1, pw = (t+1)&1;
        Ph J{nullptr, 0, P(4+pw), P(6+pr), 8, 8, g.W[6], g.W[7], H, H,
             gb0 + (size_t)h*64, g.bs + 3072, P(6+pw), 0, nullptr, nullptr, 0};
        if (h == 0) run_layer<1>(lds, J, tid, w, lr, lc, n, cD0);
        else        run_layer<1>(lds, J, tid, w, lr, lc, n, cD1);
      }
    }
    // slice barrier: no fences / cache maintenance. Drain this wave's stores to the
    // coherent point, sync the block, then one relaxed agent-scope add + spin.
    asm volatile("s_waitcnt vmcnt(0)" ::: "memory");
    __syncthreads();
    if (tid == 0){
      __hip_atomic_fetch_add(cnt, 1u, __ATOMIC_RELAXED, __HIP_MEMORY_SCOPE_AGENT);
      const u32 tgt = 16u * (u32)(p + 1);
      while (__hip_atomic_load(cnt, __ATOMIC_RELAXED, __HIP_MEMORY_SCOPE_AGENT) < tgt)
        __builtin_amdgcn_s_sleep(1);
    }
    __syncthreads();
  }
}

extern "C" void kernel_launch(void* const* d_in, const int* in_sizes, int n_in,
                              void* d_out, int out_size, void* d_ws, size_t ws_size,
                              hipStream_t stream)
{
  const float* x     = (const float*)d_in[0];
  const float* eWih0 = (const float*)d_in[1];
  const float* eWhh0 = (const float*)d_in[2];
  const float* ebih0 = (const float*)d_in[3];
  const float* ebhh0 = (const float*)d_in[4];
  const float* eWih1 = (const float*)d_in[5];
  const float* eWhh1 = (const float*)d_in[6];
  const float* ebih1 = (const float*)d_in[7];
  const float* ebhh1 = (const float*)d_in[8];
  const float* dWih0 = (const float*)d_in[9];
  const float* dWhh0 = (const float*)d_in[10];
  const float* dbih0 = (const float*)d_in[11];
  const float* dbhh0 = (const float*)d_in[12];
  const float* dWih1 = (const float*)d_in[13];
  const float* dWhh1 = (const float*)d_in[14];
  const float* dbih1 = (const float*)d_in[15];
  const float* dbhh1 = (const float*)d_in[16];
  const float* Wout  = (const float*)d_in[17];
  const float* bout  = (const float*)d_in[18];
  float* out = (float*)d_out;

  // ---- workspace layout ----
  u16* wc = (u16*)d_ws;
  const int szW[9] = {4*H*D, 4*H*H, 4*H*H, 4*H*H, 4*H*H, 4*H*H, 4*H*H, 4*H*H, D*H};
  const float* srcW[9] = {eWih0,eWhh0,eWih1,eWhh1,dWih0,dWhh0,dWih1,dWhh1,Wout};
  u16* dstW[9]; size_t woff = 0;
  for (int i = 0; i < 9; ++i){ dstW[i] = wc + woff; woff += (size_t)szW[i]; }
  woff = (woff + 7) & ~(size_t)7;
  float* bs = (float*)(wc + woff);
  u32* pl  = (u32*)(bs + 4*1024);     // planes P0..P8 (9*PH u32), then counters
  u32* cnt = pl + 9*PH;               // 16 slices x 64 u32

  for (int i = 0; i < 9; ++i)
    cvtk<<<dim3((szW[i]+1023)/1024), dim3(256), 0, stream>>>(srcW[i], dstW[i], szW[i]);
  addk<<<dim3(4), dim3(256), 0, stream>>>(ebih0, ebhh0, bs,        1024);
  addk<<<dim3(4), dim3(256), 0, stream>>>(ebih1, ebhh1, bs + 1024, 1024);
  addk<<<dim3(4), dim3(256), 0, stream>>>(dbih0, dbhh0, bs + 2048, 1024);
  addk<<<dim3(4), dim3(256), 0, stream>>>(dbih1, dbhh1, bs + 3072, 1024);
  // zero ALL planes (incl. sink) AND barrier counters — counters must restart at 0
  // every call (graph replays included)
  hipMemsetAsync(pl, 0, (9*PH + 1024) * sizeof(u32), stream);

  GG g;
  g.x = x;
  for (int i = 0; i < 9; ++i) g.W[i] = dstW[i];
  g.bs = bs; g.bout = bout;
  g.P = pl; g.out = out; g.cnt = cnt;

  persist<<<dim3(256), dim3(512), 0, stream>>>(g);
}